// Round 1
// baseline (18436.203 us; speedup 1.0000x reference)
//
#include <hip/hip_runtime.h>
#include <math.h>

#define N_M 100000
#define N_J 100000
#define NE  1600000
#define DD  64
#define HH  64

__device__ __forceinline__ float lrelu(float a){ return a > 0.f ? a : 0.2f*a; }

// order-preserving float<->uint mapping for atomicMax on floats (incl. negatives)
__device__ __forceinline__ unsigned ford(float f){
    unsigned b = __float_as_uint(f);
    return (b & 0x80000000u) ? ~b : (b | 0x80000000u);
}
__device__ __forceinline__ float funord(unsigned u){
    return (u & 0x80000000u) ? __uint_as_float(u & 0x7fffffffu) : __uint_as_float(~u);
}

// v_dst[d] = sum_h w_dst[d][h] * att_dst[h]
__global__ void k_vdst(const float* __restrict__ w_dst, const float* __restrict__ att_dst,
                       float* __restrict__ v_dst){
    int d = threadIdx.x;
    float s = 0.f;
    for (int h = 0; h < HH; ++h) s += w_dst[d*HH + h] * att_dst[h];
    v_dst[d] = s;
}

// hs = x @ w_src ; as_ = hs . att_src ; ad_ = x . v_dst
__global__ __launch_bounds__(256) void k_muon_prep(
    const float* __restrict__ x, const float* __restrict__ w_src,
    const float* __restrict__ att_src, const float* __restrict__ v_dst,
    float* __restrict__ hs, float* __restrict__ as_, float* __restrict__ ad_)
{
    __shared__ float lw[DD*HH];
    __shared__ float latt[HH];
    __shared__ float lvd[DD];
    int tid = threadIdx.x;
    for (int i = tid; i < DD*HH; i += 256) lw[i] = w_src[i];
    if (tid < HH) latt[tid] = att_src[tid];
    if (tid < DD) lvd[tid] = v_dst[tid];
    __syncthreads();
    int row = blockIdx.x*64 + (tid >> 2);
    int q = tid & 3;
    if (row >= N_M) return;
    const float4* x4 = (const float4*)(x + (size_t)row*DD);
    float acc[16];
    #pragma unroll
    for (int f = 0; f < 16; ++f) acc[f] = 0.f;
    float adp = 0.f;
    for (int kk = 0; kk < 16; ++kk){
        float4 xv = x4[kk];
        adp += xv.x*lvd[4*kk] + xv.y*lvd[4*kk+1] + xv.z*lvd[4*kk+2] + xv.w*lvd[4*kk+3];
        float xs[4] = {xv.x, xv.y, xv.z, xv.w};
        #pragma unroll
        for (int j = 0; j < 4; ++j){
            const float* wp = lw + (4*kk + j)*HH + (q << 4);
            float xk = xs[j];
            #pragma unroll
            for (int f = 0; f < 16; ++f) acc[f] = fmaf(xk, wp[f], acc[f]);
        }
    }
    float asp = 0.f;
    #pragma unroll
    for (int f = 0; f < 16; ++f) asp += acc[f] * latt[(q<<4) + f];
    asp += __shfl_xor(asp, 1);
    asp += __shfl_xor(asp, 2);
    float* hp = hs + (size_t)row*HH + (q << 4);
    #pragma unroll
    for (int j = 0; j < 4; ++j)
        ((float4*)hp)[j] = make_float4(acc[4*j], acc[4*j+1], acc[4*j+2], acc[4*j+3]);
    if (q == 0){ as_[row] = asp; ad_[row] = adp; }
}

// xw = x_jets @ gcn_w ; deg init to 1 (self loop)
__global__ __launch_bounds__(256) void k_gcn_xw(
    const float* __restrict__ x, const float* __restrict__ w,
    float* __restrict__ xw, float* __restrict__ deg)
{
    __shared__ float lw[DD*HH];
    int tid = threadIdx.x;
    for (int i = tid; i < DD*HH; i += 256) lw[i] = w[i];
    __syncthreads();
    int row = blockIdx.x*64 + (tid >> 2);
    int q = tid & 3;
    if (row >= N_J) return;
    const float4* x4 = (const float4*)(x + (size_t)row*DD);
    float acc[16];
    #pragma unroll
    for (int f = 0; f < 16; ++f) acc[f] = 0.f;
    for (int kk = 0; kk < 16; ++kk){
        float4 xv = x4[kk];
        float xs[4] = {xv.x, xv.y, xv.z, xv.w};
        #pragma unroll
        for (int j = 0; j < 4; ++j){
            const float* wp = lw + (4*kk + j)*HH + (q << 4);
            float xk = xs[j];
            #pragma unroll
            for (int f = 0; f < 16; ++f) acc[f] = fmaf(xk, wp[f], acc[f]);
        }
    }
    float* hp = xw + (size_t)row*HH + (q << 4);
    #pragma unroll
    for (int j = 0; j < 4; ++j)
        ((float4*)hp)[j] = make_float4(acc[4*j], acc[4*j+1], acc[4*j+2], acc[4*j+3]);
    if (q == 0) deg[row] = 1.0f;
}

// m init with self-loop attention value
__global__ void k_gat_minit(const float* __restrict__ as_, const float* __restrict__ ad_,
                            unsigned* __restrict__ m_u){
    int i = blockIdx.x*256 + threadIdx.x;
    if (i < N_M) m_u[i] = ford(lrelu(as_[i] + ad_[i]));
}

__global__ void k_gat_max(const int* __restrict__ ei, const float* __restrict__ as_,
                          const float* __restrict__ ad_, unsigned* __restrict__ m_u){
    int e = blockIdx.x*256 + threadIdx.x;
    if (e >= NE) return;
    int s = ei[e], d = ei[NE + e];
    atomicMax(&m_u[d], ford(lrelu(as_[s] + ad_[d])));
}

// per (edge incl self loops) x 4 feature-groups: z += ea, S += ea*hs[src]
__global__ __launch_bounds__(256) void k_gat_scatter(
    const int* __restrict__ ei, const float* __restrict__ as_,
    const float* __restrict__ ad_, const unsigned* __restrict__ m_u,
    const float* __restrict__ hs, float* __restrict__ z, float* __restrict__ S)
{
    int t = blockIdx.x*256 + threadIdx.x;
    int e = t >> 2, q = t & 3;
    if (e >= NE + N_M) return;
    int s, d;
    if (e < NE){ s = ei[e]; d = ei[NE + e]; } else { s = e - NE; d = s; }
    float a = lrelu(as_[s] + ad_[d]);
    float ea = expf(a - funord(m_u[d]));
    if (q == 0) atomicAdd(&z[d], ea);
    const float4* h4 = (const float4*)(hs + (size_t)s*HH + (q << 4));
    float* Sp = S + (size_t)d*HH + (q << 4);
    #pragma unroll
    for (int j = 0; j < 4; ++j){
        float4 v = h4[j];
        atomicAdd(Sp + 4*j + 0, ea*v.x);
        atomicAdd(Sp + 4*j + 1, ea*v.y);
        atomicAdd(Sp + 4*j + 2, ea*v.z);
        atomicAdd(Sp + 4*j + 3, ea*v.w);
    }
}

__global__ void k_gcn_deg(const int* __restrict__ ei, float* __restrict__ deg){
    int e = blockIdx.x*256 + threadIdx.x;
    if (e >= NE) return;
    atomicAdd(&deg[ei[NE + e]], 1.0f);
}

__global__ void k_dis(const float* __restrict__ deg, float* __restrict__ dis){
    int i = blockIdx.x*256 + threadIdx.x;
    if (i < N_J) dis[i] = rsqrtf(deg[i]);
}

__global__ __launch_bounds__(256) void k_gcn_scatter(
    const int* __restrict__ ei, const float* __restrict__ dis,
    const float* __restrict__ xw, float* __restrict__ S)
{
    int t = blockIdx.x*256 + threadIdx.x;
    int e = t >> 2, q = t & 3;
    if (e >= NE + N_J) return;
    int s, d;
    if (e < NE){ s = ei[e]; d = ei[NE + e]; } else { s = e - NE; d = s; }
    float norm = dis[s] * dis[d];
    const float4* h4 = (const float4*)(xw + (size_t)s*HH + (q << 4));
    float* Sp = S + (size_t)d*HH + (q << 4);
    #pragma unroll
    for (int j = 0; j < 4; ++j){
        float4 v = h4[j];
        atomicAdd(Sp + 4*j + 0, norm*v.x);
        atomicAdd(Sp + 4*j + 1, norm*v.y);
        atomicAdd(Sp + 4*j + 2, norm*v.z);
        atomicAdd(Sp + 4*j + 3, norm*v.w);
    }
}

__global__ __launch_bounds__(256) void k_sage_scatter(
    const int* __restrict__ ei, const float* __restrict__ x_m,
    float* __restrict__ agg, float* __restrict__ cnt)
{
    int t = blockIdx.x*256 + threadIdx.x;
    int e = t >> 2, q = t & 3;
    if (e >= NE) return;
    int s = ei[e], d = ei[NE + e];
    if (q == 0) atomicAdd(&cnt[d], 1.0f);
    const float4* h4 = (const float4*)(x_m + (size_t)s*DD + (q << 4));
    float* Sp = agg + (size_t)d*HH + (q << 4);
    #pragma unroll
    for (int j = 0; j < 4; ++j){
        float4 v = h4[j];
        atomicAdd(Sp + 4*j + 0, v.x);
        atomicAdd(Sp + 4*j + 1, v.y);
        atomicAdd(Sp + 4*j + 2, v.z);
        atomicAdd(Sp + 4*j + 3, v.w);
    }
}

// muons epilogue: relu(S/z + bias) -> lin -> sigmoid
__global__ __launch_bounds__(256) void k_muon_out(
    const float* __restrict__ S, const float* __restrict__ z,
    const float* __restrict__ gat_bias, const float* __restrict__ lin_w,
    const float* __restrict__ lin_b, float* __restrict__ out)
{
    __shared__ float lb[HH], llw[HH*2], llb[2];
    int tid = threadIdx.x;
    if (tid < HH) lb[tid] = gat_bias[tid];
    if (tid < HH*2) llw[tid] = lin_w[tid];
    if (tid < 2) llb[tid] = lin_b[tid];
    __syncthreads();
    int row = blockIdx.x*64 + (tid >> 2);
    int q = tid & 3;
    if (row >= N_M) return;
    float rinv = 1.f / z[row];
    const float4* S4 = (const float4*)(S + (size_t)row*HH + (q << 4));
    float p0 = 0.f, p1 = 0.f;
    #pragma unroll
    for (int j = 0; j < 4; ++j){
        float4 v = S4[j];
        float vs[4] = {v.x, v.y, v.z, v.w};
        #pragma unroll
        for (int c = 0; c < 4; ++c){
            int f = (q << 4) + 4*j + c;
            float val = fmaxf(vs[c]*rinv + lb[f], 0.f);
            p0 += val * llw[f*2 + 0];
            p1 += val * llw[f*2 + 1];
        }
    }
    p0 += __shfl_xor(p0, 1); p0 += __shfl_xor(p0, 2);
    p1 += __shfl_xor(p1, 1); p1 += __shfl_xor(p1, 2);
    if (q == 0){
        size_t o = (size_t)row * 2;
        out[o]     = 1.f/(1.f + expf(-(p0 + llb[0])));
        out[o + 1] = 1.f/(1.f + expf(-(p1 + llb[1])));
    }
}

// jets epilogue: relu(mean@w_l + x@w_r + sage_b + S_gcn + gcn_b) -> lin -> sigmoid
__global__ __launch_bounds__(256) void k_jet_out(
    const float* __restrict__ x_jets, const float* __restrict__ agg,
    const float* __restrict__ cnt, const float* __restrict__ S_gcn,
    const float* __restrict__ w_l, const float* __restrict__ w_r,
    const float* __restrict__ sage_bias, const float* __restrict__ gcn_bias,
    const float* __restrict__ lin_w, const float* __restrict__ lin_b,
    float* __restrict__ out)
{
    __shared__ float lwl[DD*HH];
    __shared__ float lwr[DD*HH];
    __shared__ float lsb[HH], lgb[HH], llw[HH*2], llb[2];
    int tid = threadIdx.x;
    for (int i = tid; i < DD*HH; i += 256){ lwl[i] = w_l[i]; lwr[i] = w_r[i]; }
    if (tid < HH){ lsb[tid] = sage_bias[tid]; lgb[tid] = gcn_bias[tid]; }
    if (tid < HH*2) llw[tid] = lin_w[tid];
    if (tid < 2) llb[tid] = lin_b[tid];
    __syncthreads();
    int row = blockIdx.x*64 + (tid >> 2);
    int q = tid & 3;
    if (row >= N_J) return;
    float inv = 1.f / fmaxf(cnt[row], 1.f);
    float acc[16];
    const float4* S4 = (const float4*)(S_gcn + (size_t)row*HH + (q << 4));
    #pragma unroll
    for (int j = 0; j < 4; ++j){
        float4 v = S4[j];
        float vs[4] = {v.x, v.y, v.z, v.w};
        #pragma unroll
        for (int c = 0; c < 4; ++c){
            int f = (q << 4) + 4*j + c;
            acc[4*j + c] = vs[c] + lgb[f] + lsb[f];
        }
    }
    const float4* a4 = (const float4*)(agg + (size_t)row*HH);
    const float4* x4 = (const float4*)(x_jets + (size_t)row*DD);
    for (int kk = 0; kk < 16; ++kk){
        float4 av = a4[kk];
        float4 xv = x4[kk];
        float ms[4] = {av.x*inv, av.y*inv, av.z*inv, av.w*inv};
        float xsv[4] = {xv.x, xv.y, xv.z, xv.w};
        #pragma unroll
        for (int j = 0; j < 4; ++j){
            const float* wl = lwl + (4*kk + j)*HH + (q << 4);
            const float* wr = lwr + (4*kk + j)*HH + (q << 4);
            #pragma unroll
            for (int f = 0; f < 16; ++f)
                acc[f] = fmaf(ms[j], wl[f], fmaf(xsv[j], wr[f], acc[f]));
        }
    }
    float p0 = 0.f, p1 = 0.f;
    #pragma unroll
    for (int f = 0; f < 16; ++f){
        float v = fmaxf(acc[f], 0.f);
        int g = (q << 4) + f;
        p0 += v * llw[g*2 + 0];
        p1 += v * llw[g*2 + 1];
    }
    p0 += __shfl_xor(p0, 1); p0 += __shfl_xor(p0, 2);
    p1 += __shfl_xor(p1, 1); p1 += __shfl_xor(p1, 2);
    if (q == 0){
        size_t o = (size_t)(N_M + row) * 2;
        out[o]     = 1.f/(1.f + expf(-(p0 + llb[0])));
        out[o + 1] = 1.f/(1.f + expf(-(p1 + llb[1])));
    }
}

extern "C" void kernel_launch(void* const* d_in, const int* in_sizes, int n_in,
                              void* d_out, int out_size, void* d_ws, size_t ws_size,
                              hipStream_t stream) {
    const float* x_muons   = (const float*)d_in[0];
    const float* x_jets    = (const float*)d_in[1];
    const int*   ei_mm     = (const int*)d_in[2];
    const int*   ei_mj     = (const int*)d_in[3];
    const int*   ei_jj     = (const int*)d_in[4];
    const float* gat_w_src = (const float*)d_in[5];
    const float* gat_w_dst = (const float*)d_in[6];
    const float* gat_att_s = (const float*)d_in[7];
    const float* gat_att_d = (const float*)d_in[8];
    const float* gat_bias  = (const float*)d_in[9];
    const float* sage_w_l  = (const float*)d_in[10];
    const float* sage_w_r  = (const float*)d_in[11];
    const float* sage_bias = (const float*)d_in[12];
    const float* gcn_w     = (const float*)d_in[13];
    const float* gcn_bias  = (const float*)d_in[14];
    const float* lin_w     = (const float*)d_in[15];
    const float* lin_b     = (const float*)d_in[16];
    float* out = (float*)d_out;

    float* ws = (float*)d_ws;
    size_t o = 0;
    float*    hs    = ws + o; o += (size_t)N_M*HH;
    float*    as_   = ws + o; o += N_M;
    float*    ad_   = ws + o; o += N_M;
    unsigned* m_u   = (unsigned*)(ws + o); o += N_M;
    float*    z     = ws + o; o += N_M;
    float*    S_gat = ws + o; o += (size_t)N_M*HH;
    float*    xw    = ws + o; o += (size_t)N_J*HH;
    float*    S_gcn = ws + o; o += (size_t)N_J*HH;
    float*    deg   = ws + o; o += N_J;
    float*    dis   = ws + o; o += N_J;
    float*    agg   = ws + o; o += (size_t)N_J*HH;
    float*    cnt   = ws + o; o += N_J;
    float*    v_dst = ws + o; o += 64;

    hipMemsetAsync(S_gat, 0, (size_t)N_M*HH*sizeof(float), stream);
    hipMemsetAsync(S_gcn, 0, (size_t)N_J*HH*sizeof(float), stream);
    hipMemsetAsync(agg,   0, (size_t)N_J*HH*sizeof(float), stream);
    hipMemsetAsync(z,     0, (size_t)N_M*sizeof(float), stream);
    hipMemsetAsync(cnt,   0, (size_t)N_J*sizeof(float), stream);

    int nb64_m = (N_M + 63) / 64;
    int nb64_j = (N_J + 63) / 64;
    int nbE    = (NE + 255) / 256;
    int nb_m   = (N_M + 255) / 256;
    int nb_j   = (N_J + 255) / 256;

    k_vdst<<<1, 64, 0, stream>>>(gat_w_dst, gat_att_d, v_dst);
    k_muon_prep<<<nb64_m, 256, 0, stream>>>(x_muons, gat_w_src, gat_att_s, v_dst, hs, as_, ad_);
    k_gcn_xw<<<nb64_j, 256, 0, stream>>>(x_jets, gcn_w, xw, deg);
    k_gat_minit<<<nb_m, 256, 0, stream>>>(as_, ad_, m_u);
    k_gat_max<<<nbE, 256, 0, stream>>>(ei_mm, as_, ad_, m_u);
    {
        int T = 4*(NE + N_M);
        k_gat_scatter<<<(T + 255)/256, 256, 0, stream>>>(ei_mm, as_, ad_, m_u, hs, z, S_gat);
    }
    k_gcn_deg<<<nbE, 256, 0, stream>>>(ei_jj, deg);
    k_dis<<<nb_j, 256, 0, stream>>>(deg, dis);
    {
        int T = 4*(NE + N_J);
        k_gcn_scatter<<<(T + 255)/256, 256, 0, stream>>>(ei_jj, dis, xw, S_gcn);
    }
    {
        int T = 4*NE;
        k_sage_scatter<<<(T + 255)/256, 256, 0, stream>>>(ei_mj, x_muons, agg, cnt);
    }
    k_muon_out<<<nb64_m, 256, 0, stream>>>(S_gat, z, gat_bias, lin_w, lin_b, out);
    k_jet_out<<<nb64_j, 256, 0, stream>>>(x_jets, agg, cnt, S_gcn, sage_w_l, sage_w_r,
                                          sage_bias, gcn_bias, lin_w, lin_b, out);
}

// Round 2
// 1131.857 us; speedup vs baseline: 16.2885x; 16.2885x over previous
//
#include <hip/hip_runtime.h>
#include <math.h>

#define N_M 100000
#define N_J 100000
#define NE  1600000
#define NTOT (3*N_M)          // 300000 buckets (mm | mj | jj)
#define ETOT (3*NE)           // 4800000 edges
#define NB_SCAN 293           // ceil(300000/1024)
#define DD  64
#define HH  64

__device__ __forceinline__ float lrelu(float a){ return a > 0.f ? a : 0.2f*a; }
__device__ __forceinline__ float wmax(float v){
    #pragma unroll
    for (int o = 32; o; o >>= 1) v = fmaxf(v, __shfl_xor(v, o));
    return v;
}
__device__ __forceinline__ float wsum(float v){
    #pragma unroll
    for (int o = 32; o; o >>= 1) v += __shfl_xor(v, o);
    return v;
}
__device__ __forceinline__ float sigm(float x){ return 1.f/(1.f + expf(-x)); }

// ---------------- dense prep ----------------

// v_dst[d] = sum_h w_dst[d][h] * att_dst[h]
__global__ void k_vdst(const float* __restrict__ w_dst, const float* __restrict__ att_dst,
                       float* __restrict__ v_dst){
    int d = threadIdx.x;
    float s = 0.f;
    for (int h = 0; h < HH; ++h) s += w_dst[d*HH + h] * att_dst[h];
    v_dst[d] = s;
}

// hs = x @ w_src ; as_ = hs . att_src ; ad_ = x . v_dst
__global__ __launch_bounds__(256) void k_muon_prep(
    const float* __restrict__ x, const float* __restrict__ w_src,
    const float* __restrict__ att_src, const float* __restrict__ v_dst,
    float* __restrict__ hs, float* __restrict__ as_, float* __restrict__ ad_)
{
    __shared__ float lw[DD*HH];
    __shared__ float latt[HH];
    __shared__ float lvd[DD];
    int tid = threadIdx.x;
    for (int i = tid; i < DD*HH; i += 256) lw[i] = w_src[i];
    if (tid < HH) latt[tid] = att_src[tid];
    if (tid < DD) lvd[tid] = v_dst[tid];
    __syncthreads();
    int row = blockIdx.x*64 + (tid >> 2);
    int q = tid & 3;
    if (row >= N_M) return;
    const float4* x4 = (const float4*)(x + (size_t)row*DD);
    float acc[16];
    #pragma unroll
    for (int f = 0; f < 16; ++f) acc[f] = 0.f;
    float adp = 0.f;
    for (int kk = 0; kk < 16; ++kk){
        float4 xv = x4[kk];
        adp += xv.x*lvd[4*kk] + xv.y*lvd[4*kk+1] + xv.z*lvd[4*kk+2] + xv.w*lvd[4*kk+3];
        float xs[4] = {xv.x, xv.y, xv.z, xv.w};
        #pragma unroll
        for (int j = 0; j < 4; ++j){
            const float* wp = lw + (4*kk + j)*HH + (q << 4);
            float xk = xs[j];
            #pragma unroll
            for (int f = 0; f < 16; ++f) acc[f] = fmaf(xk, wp[f], acc[f]);
        }
    }
    float asp = 0.f;
    #pragma unroll
    for (int f = 0; f < 16; ++f) asp += acc[f] * latt[(q<<4) + f];
    asp += __shfl_xor(asp, 1);
    asp += __shfl_xor(asp, 2);
    float* hp = hs + (size_t)row*HH + (q << 4);
    #pragma unroll
    for (int j = 0; j < 4; ++j)
        ((float4*)hp)[j] = make_float4(acc[4*j], acc[4*j+1], acc[4*j+2], acc[4*j+3]);
    if (q == 0){ as_[row] = asp; ad_[row] = adp; }
}

// xw = x_jets @ gcn_w
__global__ __launch_bounds__(256) void k_gcn_xw(
    const float* __restrict__ x, const float* __restrict__ w, float* __restrict__ xw)
{
    __shared__ float lw[DD*HH];
    int tid = threadIdx.x;
    for (int i = tid; i < DD*HH; i += 256) lw[i] = w[i];
    __syncthreads();
    int row = blockIdx.x*64 + (tid >> 2);
    int q = tid & 3;
    if (row >= N_J) return;
    const float4* x4 = (const float4*)(x + (size_t)row*DD);
    float acc[16];
    #pragma unroll
    for (int f = 0; f < 16; ++f) acc[f] = 0.f;
    for (int kk = 0; kk < 16; ++kk){
        float4 xv = x4[kk];
        float xs[4] = {xv.x, xv.y, xv.z, xv.w};
        #pragma unroll
        for (int j = 0; j < 4; ++j){
            const float* wp = lw + (4*kk + j)*HH + (q << 4);
            float xk = xs[j];
            #pragma unroll
            for (int f = 0; f < 16; ++f) acc[f] = fmaf(xk, wp[f], acc[f]);
        }
    }
    float* hp = xw + (size_t)row*HH + (q << 4);
    #pragma unroll
    for (int j = 0; j < 4; ++j)
        ((float4*)hp)[j] = make_float4(acc[4*j], acc[4*j+1], acc[4*j+2], acc[4*j+3]);
}

// ---------------- CSR build (all 3 relations concatenated) ----------------

__global__ void k_hist(const int* __restrict__ ei_mm, const int* __restrict__ ei_mj,
                       const int* __restrict__ ei_jj, int* __restrict__ cnt){
    int t = blockIdx.x*256 + threadIdx.x;
    if (t >= ETOT) return;
    int r = t / NE;
    int e = t - r*NE;
    const int* ei = (r == 0) ? ei_mm : ((r == 1) ? ei_mj : ei_jj);
    int d = ei[NE + e];
    atomicAdd(&cnt[r*N_M + d], 1);
}

__global__ __launch_bounds__(256) void k_scan1(const int* __restrict__ cnt,
                                               int* __restrict__ offs, int* __restrict__ bsum){
    __shared__ int ls[256];
    int b = blockIdx.x, t = threadIdx.x;
    int base = b*1024 + t*4;
    int4 c = make_int4(0,0,0,0);
    if (base < NTOT) c = *(const int4*)(cnt + base);
    int s = c.x + c.y + c.z + c.w;
    ls[t] = s; __syncthreads();
    for (int o = 1; o < 256; o <<= 1){
        int a = (t >= o) ? ls[t - o] : 0;
        __syncthreads();
        ls[t] += a;
        __syncthreads();
    }
    int excl = ls[t] - s;
    if (t == 255) bsum[b] = ls[255];
    if (base < NTOT){
        offs[base]   = excl;
        offs[base+1] = excl + c.x;
        offs[base+2] = excl + c.x + c.y;
        offs[base+3] = excl + c.x + c.y + c.z;
    }
}

__global__ __launch_bounds__(512) void k_scan2(int* __restrict__ bsum){
    __shared__ int ls[512];
    int t = threadIdx.x;
    int v = (t < NB_SCAN) ? bsum[t] : 0;
    ls[t] = v; __syncthreads();
    for (int o = 1; o < 512; o <<= 1){
        int a = (t >= o) ? ls[t - o] : 0;
        __syncthreads();
        ls[t] += a;
        __syncthreads();
    }
    if (t < NB_SCAN) bsum[t] = ls[t] - v;  // exclusive
}

__global__ void k_scan3(int* __restrict__ offs, const int* __restrict__ bsum){
    int b = blockIdx.x, t = threadIdx.x;
    int base = b*1024 + t*4;
    if (base >= NTOT) return;
    int add = bsum[b];
    int4* p = (int4*)(offs + base);
    int4 v = *p;
    v.x += add; v.y += add; v.z += add; v.w += add;
    *p = v;
}

__global__ void k_fill(const int* __restrict__ ei_mm, const int* __restrict__ ei_mj,
                       const int* __restrict__ ei_jj, const int* __restrict__ offs,
                       int* __restrict__ cursor, int* __restrict__ perm){
    int t = blockIdx.x*256 + threadIdx.x;
    if (t >= ETOT) return;
    int r = t / NE;
    int e = t - r*NE;
    const int* ei = (r == 0) ? ei_mm : ((r == 1) ? ei_mj : ei_jj);
    int s = ei[e];
    int d = ei[NE + e];
    int bkt = r*N_M + d;
    int pos = atomicAdd(&cursor[bkt], 1);
    perm[offs[bkt] + pos] = s;   // store SOURCE node id
}

// dis[j] = rsqrt(in-degree(jj) + 1)
__global__ void k_dis(const int* __restrict__ offs, float* __restrict__ dis){
    int j = blockIdx.x*256 + threadIdx.x;
    if (j >= N_J) return;
    int beg = offs[2*N_M + j];
    int end = (j == N_J-1) ? ETOT : offs[2*N_M + j + 1];
    dis[j] = rsqrtf((float)(end - beg + 1));
}

// ---------------- fused gather + epilogue ----------------

// muons: GAT (in-register softmax) -> relu -> lin -> sigmoid
__global__ __launch_bounds__(256) void k_muon_gat_out(
    const int* __restrict__ offs, const int* __restrict__ perm,
    const float* __restrict__ as_, const float* __restrict__ ad_,
    const float* __restrict__ hs, const float* __restrict__ gat_bias,
    const float* __restrict__ lin_w, const float* __restrict__ lin_b,
    float* __restrict__ out)
{
    int wid = threadIdx.x >> 6;
    int l = threadIdx.x & 63;
    int d = blockIdx.x*4 + wid;
    if (d >= N_M) return;
    int beg = offs[d], end = offs[d+1];
    float ad_d = ad_[d];
    float a_self = lrelu(as_[d] + ad_d);
    // pass 1: segment max (incl self loop)
    float am = a_self;
    for (int base = beg; base < end; base += 64){
        int e = base + l;
        if (e < end){
            int s = perm[e];
            am = fmaxf(am, lrelu(as_[s] + ad_d));
        }
    }
    float m = wmax(am);
    // pass 2: ea + weighted feature gather
    float eself = expf(a_self - m);
    float z = eself;
    float acc = eself * hs[(size_t)d*HH + l];
    for (int base = beg; base < end; base += 64){
        int e = base + l;
        int sB = 0; float eaB = 0.f;
        if (e < end){
            sB = perm[e];
            eaB = expf(lrelu(as_[sB] + ad_d) - m);
        }
        int cc = min(64, end - base);
        for (int k = 0; k < cc; ++k){
            int sk = __shfl(sB, k);
            float eak = __shfl(eaB, k);
            z += eak;
            acc = fmaf(eak, hs[(size_t)sk*HH + l], acc);
        }
    }
    float val = fmaxf(acc / z + gat_bias[l], 0.f);
    float p0 = wsum(val * lin_w[l*2 + 0]);
    float p1 = wsum(val * lin_w[l*2 + 1]);
    if (l == 0){
        size_t o = (size_t)d*2;
        out[o]   = sigm(p0 + lin_b[0]);
        out[o+1] = sigm(p1 + lin_b[1]);
    }
}

// jets: SAGE mean gather + GCN gather + dense transforms -> relu -> lin -> sigmoid
__global__ __launch_bounds__(256) void k_jet_out(
    const float* __restrict__ x_jets, const float* __restrict__ x_muons,
    const float* __restrict__ xw, const float* __restrict__ dis,
    const int* __restrict__ offs, const int* __restrict__ perm,
    const float* __restrict__ w_l, const float* __restrict__ w_r,
    const float* __restrict__ sage_bias, const float* __restrict__ gcn_bias,
    const float* __restrict__ lin_w, const float* __restrict__ lin_b,
    float* __restrict__ out)
{
    __shared__ float lwl[DD*HH];
    __shared__ float lwr[DD*HH];
    int tid = threadIdx.x;
    for (int i = tid; i < DD*HH; i += 256){ lwl[i] = w_l[i]; lwr[i] = w_r[i]; }
    __syncthreads();
    int wid = tid >> 6;
    int l = tid & 63;
    int j = blockIdx.x*4 + wid;
    if (j >= N_J) return;
    // ---- SAGE gather (mj relation, buckets N_M..2N_M) ----
    int beg = offs[N_M + j], end = offs[N_M + j + 1];
    float accs = 0.f;
    for (int base = beg; base < end; base += 64){
        int e = base + l;
        int sB = (e < end) ? perm[e] : -1;
        int cc = min(64, end - base);
        for (int k = 0; k < cc; ++k){
            int sk = __shfl(sB, k);
            accs += x_muons[(size_t)sk*DD + l];
        }
    }
    float inv = (end > beg) ? 1.f/(float)(end - beg) : 1.f;
    float mean = accs * inv;
    // ---- GCN gather (jj relation, buckets 2N_M..3N_M) ----
    int beg2 = offs[2*N_M + j];
    int end2 = (j == N_J-1) ? ETOT : offs[2*N_M + j + 1];
    float dj = dis[j];
    float accg = dj*dj*xw[(size_t)j*HH + l];   // self loop
    for (int base = beg2; base < end2; base += 64){
        int e = base + l;
        int sB = 0; float nB = 0.f;
        if (e < end2){ sB = perm[e]; nB = dis[sB]*dj; }
        int cc = min(64, end2 - base);
        for (int k = 0; k < cc; ++k){
            int sk = __shfl(sB, k);
            float nk = __shfl(nB, k);
            accg = fmaf(nk, xw[(size_t)sk*HH + l], accg);
        }
    }
    // ---- mean @ w_l + x_j @ w_r (per-row matvec via broadcast) ----
    float xv = x_jets[(size_t)j*DD + l];
    float accf = accg + gcn_bias[l] + sage_bias[l];
    for (int k = 0; k < 64; ++k){
        float mk = __shfl(mean, k);
        float xk = __shfl(xv, k);
        accf = fmaf(mk, lwl[k*64 + l], fmaf(xk, lwr[k*64 + l], accf));
    }
    float val = fmaxf(accf, 0.f);
    float p0 = wsum(val * lin_w[l*2 + 0]);
    float p1 = wsum(val * lin_w[l*2 + 1]);
    if (l == 0){
        size_t o = (size_t)(N_M + j)*2;
        out[o]   = sigm(p0 + lin_b[0]);
        out[o+1] = sigm(p1 + lin_b[1]);
    }
}

extern "C" void kernel_launch(void* const* d_in, const int* in_sizes, int n_in,
                              void* d_out, int out_size, void* d_ws, size_t ws_size,
                              hipStream_t stream) {
    const float* x_muons   = (const float*)d_in[0];
    const float* x_jets    = (const float*)d_in[1];
    const int*   ei_mm     = (const int*)d_in[2];
    const int*   ei_mj     = (const int*)d_in[3];
    const int*   ei_jj     = (const int*)d_in[4];
    const float* gat_w_src = (const float*)d_in[5];
    const float* gat_w_dst = (const float*)d_in[6];
    const float* gat_att_s = (const float*)d_in[7];
    const float* gat_att_d = (const float*)d_in[8];
    const float* gat_bias  = (const float*)d_in[9];
    const float* sage_w_l  = (const float*)d_in[10];
    const float* sage_w_r  = (const float*)d_in[11];
    const float* sage_bias = (const float*)d_in[12];
    const float* gcn_w     = (const float*)d_in[13];
    const float* gcn_bias  = (const float*)d_in[14];
    const float* lin_w     = (const float*)d_in[15];
    const float* lin_b     = (const float*)d_in[16];
    float* out = (float*)d_out;

    float* ws = (float*)d_ws;
    size_t o = 0;
    float* hs    = ws + o; o += (size_t)N_M*HH;
    float* as_   = ws + o; o += N_M;
    float* ad_   = ws + o; o += N_M;
    float* xw    = ws + o; o += (size_t)N_J*HH;
    float* dis   = ws + o; o += N_J;
    float* v_dst = ws + o; o += 64;
    int* cnt    = (int*)(ws + o); o += NTOT;
    int* offs   = (int*)(ws + o); o += NTOT + 4;
    int* cursor = (int*)(ws + o); o += NTOT;
    int* bsum   = (int*)(ws + o); o += 512;
    int* perm   = (int*)(ws + o); o += ETOT;

    hipMemsetAsync(cnt,    0, (size_t)NTOT*sizeof(int), stream);
    hipMemsetAsync(cursor, 0, (size_t)NTOT*sizeof(int), stream);

    int nb64_m = (N_M + 63) / 64;
    int nb64_j = (N_J + 63) / 64;
    int nbE3   = (ETOT + 255) / 256;

    k_vdst<<<1, 64, 0, stream>>>(gat_w_dst, gat_att_d, v_dst);
    k_muon_prep<<<nb64_m, 256, 0, stream>>>(x_muons, gat_w_src, gat_att_s, v_dst, hs, as_, ad_);
    k_gcn_xw<<<nb64_j, 256, 0, stream>>>(x_jets, gcn_w, xw);

    k_hist<<<nbE3, 256, 0, stream>>>(ei_mm, ei_mj, ei_jj, cnt);
    k_scan1<<<NB_SCAN, 256, 0, stream>>>(cnt, offs, bsum);
    k_scan2<<<1, 512, 0, stream>>>(bsum);
    k_scan3<<<NB_SCAN, 256, 0, stream>>>(offs, bsum);
    k_fill<<<nbE3, 256, 0, stream>>>(ei_mm, ei_mj, ei_jj, offs, cursor, perm);
    k_dis<<<(N_J + 255)/256, 256, 0, stream>>>(offs, dis);

    k_muon_gat_out<<<N_M/4, 256, 0, stream>>>(offs, perm, as_, ad_, hs,
                                              gat_bias, lin_w, lin_b, out);
    k_jet_out<<<N_J/4, 256, 0, stream>>>(x_jets, x_muons, xw, dis, offs, perm,
                                         sage_w_l, sage_w_r, sage_bias, gcn_bias,
                                         lin_w, lin_b, out);
}

// Round 3
// 908.179 us; speedup vs baseline: 20.3002x; 1.2463x over previous
//
#include <hip/hip_runtime.h>
#include <math.h>

#define N_M 100000
#define N_J 100000
#define NE  1600000
#define NTOT (3*N_M)          // 300000 buckets (mm | mj | jj)
#define ETOT (3*NE)           // 4800000 edges
#define NB_SCAN 293           // ceil(300000/1024)
#define DD  64
#define HH  64

__device__ __forceinline__ float lrelu(float a){ return a > 0.f ? a : 0.2f*a; }
__device__ __forceinline__ float wmax(float v){
    #pragma unroll
    for (int o = 32; o; o >>= 1) v = fmaxf(v, __shfl_xor(v, o));
    return v;
}
__device__ __forceinline__ float wsum(float v){
    #pragma unroll
    for (int o = 32; o; o >>= 1) v += __shfl_xor(v, o);
    return v;
}
__device__ __forceinline__ float sigm(float x){ return 1.f/(1.f + expf(-x)); }

// ---------------- dense prep ----------------

// v_dst[d] = sum_h w_dst[d][h] * att_dst[h]
__global__ void k_vdst(const float* __restrict__ w_dst, const float* __restrict__ att_dst,
                       float* __restrict__ v_dst){
    int d = threadIdx.x;
    float s = 0.f;
    for (int h = 0; h < HH; ++h) s += w_dst[d*HH + h] * att_dst[h];
    v_dst[d] = s;
}

// hs = x @ w_src ; as_ = hs . att_src ; ad_ = x . v_dst
__global__ __launch_bounds__(256) void k_muon_prep(
    const float* __restrict__ x, const float* __restrict__ w_src,
    const float* __restrict__ att_src, const float* __restrict__ v_dst,
    float* __restrict__ hs, float* __restrict__ as_, float* __restrict__ ad_)
{
    __shared__ float lw[DD*HH];
    __shared__ float latt[HH];
    __shared__ float lvd[DD];
    int tid = threadIdx.x;
    for (int i = tid; i < DD*HH; i += 256) lw[i] = w_src[i];
    if (tid < HH) latt[tid] = att_src[tid];
    if (tid < DD) lvd[tid] = v_dst[tid];
    __syncthreads();
    int row = blockIdx.x*64 + (tid >> 2);
    int q = tid & 3;
    if (row >= N_M) return;
    const float4* x4 = (const float4*)(x + (size_t)row*DD);
    float acc[16];
    #pragma unroll
    for (int f = 0; f < 16; ++f) acc[f] = 0.f;
    float adp = 0.f;
    for (int kk = 0; kk < 16; ++kk){
        float4 xv = x4[kk];
        adp += xv.x*lvd[4*kk] + xv.y*lvd[4*kk+1] + xv.z*lvd[4*kk+2] + xv.w*lvd[4*kk+3];
        float xs[4] = {xv.x, xv.y, xv.z, xv.w};
        #pragma unroll
        for (int j = 0; j < 4; ++j){
            const float* wp = lw + (4*kk + j)*HH + (q << 4);
            float xk = xs[j];
            #pragma unroll
            for (int f = 0; f < 16; ++f) acc[f] = fmaf(xk, wp[f], acc[f]);
        }
    }
    float asp = 0.f;
    #pragma unroll
    for (int f = 0; f < 16; ++f) asp += acc[f] * latt[(q<<4) + f];
    asp += __shfl_xor(asp, 1);
    asp += __shfl_xor(asp, 2);
    float* hp = hs + (size_t)row*HH + (q << 4);
    #pragma unroll
    for (int j = 0; j < 4; ++j)
        ((float4*)hp)[j] = make_float4(acc[4*j], acc[4*j+1], acc[4*j+2], acc[4*j+3]);
    if (q == 0){ as_[row] = asp; ad_[row] = adp; }
}

// xw = x_jets @ gcn_w
__global__ __launch_bounds__(256) void k_gcn_xw(
    const float* __restrict__ x, const float* __restrict__ w, float* __restrict__ xw)
{
    __shared__ float lw[DD*HH];
    int tid = threadIdx.x;
    for (int i = tid; i < DD*HH; i += 256) lw[i] = w[i];
    __syncthreads();
    int row = blockIdx.x*64 + (tid >> 2);
    int q = tid & 3;
    if (row >= N_J) return;
    const float4* x4 = (const float4*)(x + (size_t)row*DD);
    float acc[16];
    #pragma unroll
    for (int f = 0; f < 16; ++f) acc[f] = 0.f;
    for (int kk = 0; kk < 16; ++kk){
        float4 xv = x4[kk];
        float xs[4] = {xv.x, xv.y, xv.z, xv.w};
        #pragma unroll
        for (int j = 0; j < 4; ++j){
            const float* wp = lw + (4*kk + j)*HH + (q << 4);
            float xk = xs[j];
            #pragma unroll
            for (int f = 0; f < 16; ++f) acc[f] = fmaf(xk, wp[f], acc[f]);
        }
    }
    float* hp = xw + (size_t)row*HH + (q << 4);
    #pragma unroll
    for (int j = 0; j < 4; ++j)
        ((float4*)hp)[j] = make_float4(acc[4*j], acc[4*j+1], acc[4*j+2], acc[4*j+3]);
}

// ---------------- CSR build (all 3 relations concatenated) ----------------

__global__ void k_hist(const int* __restrict__ ei_mm, const int* __restrict__ ei_mj,
                       const int* __restrict__ ei_jj, int* __restrict__ cnt){
    int t = blockIdx.x*256 + threadIdx.x;
    if (t >= ETOT) return;
    int r = t / NE;
    int e = t - r*NE;
    const int* ei = (r == 0) ? ei_mm : ((r == 1) ? ei_mj : ei_jj);
    int d = ei[NE + e];
    atomicAdd(&cnt[r*N_M + d], 1);
}

__global__ __launch_bounds__(256) void k_scan1(const int* __restrict__ cnt,
                                               int* __restrict__ offs, int* __restrict__ bsum){
    __shared__ int ls[256];
    int b = blockIdx.x, t = threadIdx.x;
    int base = b*1024 + t*4;
    int4 c = make_int4(0,0,0,0);
    if (base < NTOT) c = *(const int4*)(cnt + base);
    int s = c.x + c.y + c.z + c.w;
    ls[t] = s; __syncthreads();
    for (int o = 1; o < 256; o <<= 1){
        int a = (t >= o) ? ls[t - o] : 0;
        __syncthreads();
        ls[t] += a;
        __syncthreads();
    }
    int excl = ls[t] - s;
    if (t == 255) bsum[b] = ls[255];
    if (base < NTOT){
        offs[base]   = excl;
        offs[base+1] = excl + c.x;
        offs[base+2] = excl + c.x + c.y;
        offs[base+3] = excl + c.x + c.y + c.z;
    }
}

__global__ __launch_bounds__(512) void k_scan2(int* __restrict__ bsum){
    __shared__ int ls[512];
    int t = threadIdx.x;
    int v = (t < NB_SCAN) ? bsum[t] : 0;
    ls[t] = v; __syncthreads();
    for (int o = 1; o < 512; o <<= 1){
        int a = (t >= o) ? ls[t - o] : 0;
        __syncthreads();
        ls[t] += a;
        __syncthreads();
    }
    if (t < NB_SCAN) bsum[t] = ls[t] - v;  // exclusive
}

__global__ void k_scan3(int* __restrict__ offs, const int* __restrict__ bsum){
    int b = blockIdx.x, t = threadIdx.x;
    int base = b*1024 + t*4;
    if (base >= NTOT) return;
    int add = bsum[b];
    int4* p = (int4*)(offs + base);
    int4 v = *p;
    v.x += add; v.y += add; v.z += add; v.w += add;
    *p = v;
}

__global__ void k_fill(const int* __restrict__ ei_mm, const int* __restrict__ ei_mj,
                       const int* __restrict__ ei_jj, const int* __restrict__ offs,
                       int* __restrict__ cursor, int* __restrict__ perm){
    int t = blockIdx.x*256 + threadIdx.x;
    if (t >= ETOT) return;
    int r = t / NE;
    int e = t - r*NE;
    const int* ei = (r == 0) ? ei_mm : ((r == 1) ? ei_mj : ei_jj);
    int s = ei[e];
    int d = ei[NE + e];
    int bkt = r*N_M + d;
    int pos = atomicAdd(&cursor[bkt], 1);
    perm[offs[bkt] + pos] = s;   // store SOURCE node id
}

// dis[j] = rsqrt(in-degree(jj) + 1)
__global__ void k_dis(const int* __restrict__ offs, float* __restrict__ dis){
    int j = blockIdx.x*256 + threadIdx.x;
    if (j >= N_J) return;
    int beg = offs[2*N_M + j];
    int end = (j == N_J-1) ? ETOT : offs[2*N_M + j + 1];
    dis[j] = rsqrtf((float)(end - beg + 1));
}

// ---------------- fused gather + epilogue ----------------

// muons: GAT (in-register softmax) -> relu -> lin -> sigmoid
__global__ __launch_bounds__(256) void k_muon_gat_out(
    const int* __restrict__ offs, const int* __restrict__ perm,
    const float* __restrict__ as_, const float* __restrict__ ad_,
    const float* __restrict__ hs, const float* __restrict__ gat_bias,
    const float* __restrict__ lin_w, const float* __restrict__ lin_b,
    float* __restrict__ out)
{
    int wid = threadIdx.x >> 6;
    int l = threadIdx.x & 63;
    int d = blockIdx.x*4 + wid;
    if (d >= N_M) return;
    int beg = offs[d], end = offs[d+1];
    float ad_d = ad_[d];
    float a_self = lrelu(as_[d] + ad_d);
    // pass 1: segment max (incl self loop) — lane-parallel
    float am = a_self;
    for (int base = beg; base < end; base += 64){
        int e = base + l;
        if (e < end) am = fmaxf(am, lrelu(as_[perm[e]] + ad_d));
    }
    float m = wmax(am);
    // pass 2: ea + weighted feature gather, 8-way unrolled for MLP
    float eself = expf(a_self - m);
    float z = eself;
    float acc0 = eself * hs[(size_t)d*HH + l], acc1 = 0.f;
    for (int base = beg; base < end; base += 64){
        int e = base + l;
        int sB = 0; float eaB = 0.f;
        if (e < end){
            sB = perm[e];
            eaB = expf(lrelu(as_[sB] + ad_d) - m);
        }
        z += wsum(eaB);
        int cc = min(64, end - base);
        int k = 0;
        for (; k + 8 <= cc; k += 8){
            int s0=__shfl(sB,k+0), s1=__shfl(sB,k+1), s2=__shfl(sB,k+2), s3=__shfl(sB,k+3);
            int s4=__shfl(sB,k+4), s5=__shfl(sB,k+5), s6=__shfl(sB,k+6), s7=__shfl(sB,k+7);
            float e0=__shfl(eaB,k+0), e1=__shfl(eaB,k+1), e2=__shfl(eaB,k+2), e3=__shfl(eaB,k+3);
            float e4=__shfl(eaB,k+4), e5=__shfl(eaB,k+5), e6=__shfl(eaB,k+6), e7=__shfl(eaB,k+7);
            float v0=hs[(size_t)s0*HH+l], v1=hs[(size_t)s1*HH+l];
            float v2=hs[(size_t)s2*HH+l], v3=hs[(size_t)s3*HH+l];
            float v4=hs[(size_t)s4*HH+l], v5=hs[(size_t)s5*HH+l];
            float v6=hs[(size_t)s6*HH+l], v7=hs[(size_t)s7*HH+l];
            acc0 = fmaf(e0,v0,acc0); acc1 = fmaf(e1,v1,acc1);
            acc0 = fmaf(e2,v2,acc0); acc1 = fmaf(e3,v3,acc1);
            acc0 = fmaf(e4,v4,acc0); acc1 = fmaf(e5,v5,acc1);
            acc0 = fmaf(e6,v6,acc0); acc1 = fmaf(e7,v7,acc1);
        }
        for (; k < cc; ++k){
            int sk = __shfl(sB, k);
            float eak = __shfl(eaB, k);
            acc0 = fmaf(eak, hs[(size_t)sk*HH + l], acc0);
        }
    }
    float val = fmaxf((acc0 + acc1) / z + gat_bias[l], 0.f);
    float p0 = wsum(val * lin_w[l*2 + 0]);
    float p1 = wsum(val * lin_w[l*2 + 1]);
    if (l == 0){
        size_t o = (size_t)d*2;
        out[o]   = sigm(p0 + lin_b[0]);
        out[o+1] = sigm(p1 + lin_b[1]);
    }
}

// jets: SAGE mean gather + GCN gather + dense transforms -> relu -> lin -> sigmoid
// 512 threads/block so the 32KB weight LDS is amortized over 8 waves (occupancy).
__global__ __launch_bounds__(512) void k_jet_out(
    const float* __restrict__ x_jets, const float* __restrict__ x_muons,
    const float* __restrict__ xw, const float* __restrict__ dis,
    const int* __restrict__ offs, const int* __restrict__ perm,
    const float* __restrict__ w_l, const float* __restrict__ w_r,
    const float* __restrict__ sage_bias, const float* __restrict__ gcn_bias,
    const float* __restrict__ lin_w, const float* __restrict__ lin_b,
    float* __restrict__ out)
{
    __shared__ float lwl[DD*HH];
    __shared__ float lwr[DD*HH];
    int tid = threadIdx.x;
    for (int i = tid; i < DD*HH; i += 512){ lwl[i] = w_l[i]; lwr[i] = w_r[i]; }
    __syncthreads();
    int wid = tid >> 6;
    int l = tid & 63;
    int j = blockIdx.x*8 + wid;
    if (j >= N_J) return;
    // ---- SAGE gather (mj relation, buckets N_M..2N_M), 8-way unrolled ----
    int beg = offs[N_M + j], end = offs[N_M + j + 1];
    float sa0 = 0.f, sa1 = 0.f;
    for (int base = beg; base < end; base += 64){
        int e = base + l;
        int sB = (e < end) ? perm[e] : 0;
        int cc = min(64, end - base);
        int k = 0;
        for (; k + 8 <= cc; k += 8){
            int s0=__shfl(sB,k+0), s1=__shfl(sB,k+1), s2=__shfl(sB,k+2), s3=__shfl(sB,k+3);
            int s4=__shfl(sB,k+4), s5=__shfl(sB,k+5), s6=__shfl(sB,k+6), s7=__shfl(sB,k+7);
            float v0=x_muons[(size_t)s0*DD+l], v1=x_muons[(size_t)s1*DD+l];
            float v2=x_muons[(size_t)s2*DD+l], v3=x_muons[(size_t)s3*DD+l];
            float v4=x_muons[(size_t)s4*DD+l], v5=x_muons[(size_t)s5*DD+l];
            float v6=x_muons[(size_t)s6*DD+l], v7=x_muons[(size_t)s7*DD+l];
            sa0 += v0 + v2; sa1 += v1 + v3;
            sa0 += v4 + v6; sa1 += v5 + v7;
        }
        for (; k < cc; ++k){
            int sk = __shfl(sB, k);
            sa0 += x_muons[(size_t)sk*DD + l];
        }
    }
    float inv = (end > beg) ? 1.f/(float)(end - beg) : 1.f;
    float mean = (sa0 + sa1) * inv;
    // ---- GCN gather (jj relation, buckets 2N_M..3N_M), 8-way unrolled ----
    int beg2 = offs[2*N_M + j];
    int end2 = (j == N_J-1) ? ETOT : offs[2*N_M + j + 1];
    float dj = dis[j];
    float g0 = dj*dj*xw[(size_t)j*HH + l], g1 = 0.f;   // self loop
    for (int base = beg2; base < end2; base += 64){
        int e = base + l;
        int sB = 0; float nB = 0.f;
        if (e < end2){ sB = perm[e]; nB = dis[sB]*dj; }
        int cc = min(64, end2 - base);
        int k = 0;
        for (; k + 8 <= cc; k += 8){
            int s0=__shfl(sB,k+0), s1=__shfl(sB,k+1), s2=__shfl(sB,k+2), s3=__shfl(sB,k+3);
            int s4=__shfl(sB,k+4), s5=__shfl(sB,k+5), s6=__shfl(sB,k+6), s7=__shfl(sB,k+7);
            float n0=__shfl(nB,k+0), n1=__shfl(nB,k+1), n2=__shfl(nB,k+2), n3=__shfl(nB,k+3);
            float n4=__shfl(nB,k+4), n5=__shfl(nB,k+5), n6=__shfl(nB,k+6), n7=__shfl(nB,k+7);
            float v0=xw[(size_t)s0*HH+l], v1=xw[(size_t)s1*HH+l];
            float v2=xw[(size_t)s2*HH+l], v3=xw[(size_t)s3*HH+l];
            float v4=xw[(size_t)s4*HH+l], v5=xw[(size_t)s5*HH+l];
            float v6=xw[(size_t)s6*HH+l], v7=xw[(size_t)s7*HH+l];
            g0 = fmaf(n0,v0,g0); g1 = fmaf(n1,v1,g1);
            g0 = fmaf(n2,v2,g0); g1 = fmaf(n3,v3,g1);
            g0 = fmaf(n4,v4,g0); g1 = fmaf(n5,v5,g1);
            g0 = fmaf(n6,v6,g0); g1 = fmaf(n7,v7,g1);
        }
        for (; k < cc; ++k){
            int sk = __shfl(sB, k);
            float nk = __shfl(nB, k);
            g0 = fmaf(nk, xw[(size_t)sk*HH + l], g0);
        }
    }
    // ---- mean @ w_l + x_j @ w_r (per-row matvec via broadcast) ----
    float xv = x_jets[(size_t)j*DD + l];
    float accf = g0 + g1 + gcn_bias[l] + sage_bias[l];
    for (int k = 0; k < 64; ++k){
        float mk = __shfl(mean, k);
        float xk = __shfl(xv, k);
        accf = fmaf(mk, lwl[k*64 + l], fmaf(xk, lwr[k*64 + l], accf));
    }
    float val = fmaxf(accf, 0.f);
    float p0 = wsum(val * lin_w[l*2 + 0]);
    float p1 = wsum(val * lin_w[l*2 + 1]);
    if (l == 0){
        size_t o = (size_t)(N_M + j)*2;
        out[o]   = sigm(p0 + lin_b[0]);
        out[o+1] = sigm(p1 + lin_b[1]);
    }
}

extern "C" void kernel_launch(void* const* d_in, const int* in_sizes, int n_in,
                              void* d_out, int out_size, void* d_ws, size_t ws_size,
                              hipStream_t stream) {
    const float* x_muons   = (const float*)d_in[0];
    const float* x_jets    = (const float*)d_in[1];
    const int*   ei_mm     = (const int*)d_in[2];
    const int*   ei_mj     = (const int*)d_in[3];
    const int*   ei_jj     = (const int*)d_in[4];
    const float* gat_w_src = (const float*)d_in[5];
    const float* gat_w_dst = (const float*)d_in[6];
    const float* gat_att_s = (const float*)d_in[7];
    const float* gat_att_d = (const float*)d_in[8];
    const float* gat_bias  = (const float*)d_in[9];
    const float* sage_w_l  = (const float*)d_in[10];
    const float* sage_w_r  = (const float*)d_in[11];
    const float* sage_bias = (const float*)d_in[12];
    const float* gcn_w     = (const float*)d_in[13];
    const float* gcn_bias  = (const float*)d_in[14];
    const float* lin_w     = (const float*)d_in[15];
    const float* lin_b     = (const float*)d_in[16];
    float* out = (float*)d_out;

    float* ws = (float*)d_ws;
    size_t o = 0;
    float* hs    = ws + o; o += (size_t)N_M*HH;
    float* as_   = ws + o; o += N_M;
    float* ad_   = ws + o; o += N_M;
    float* xw    = ws + o; o += (size_t)N_J*HH;
    float* dis   = ws + o; o += N_J;
    float* v_dst = ws + o; o += 64;
    int* cnt    = (int*)(ws + o); o += NTOT;
    int* offs   = (int*)(ws + o); o += NTOT + 4;
    int* cursor = (int*)(ws + o); o += NTOT;
    int* bsum   = (int*)(ws + o); o += 512;
    int* perm   = (int*)(ws + o); o += ETOT;

    hipMemsetAsync(cnt,    0, (size_t)NTOT*sizeof(int), stream);
    hipMemsetAsync(cursor, 0, (size_t)NTOT*sizeof(int), stream);

    int nb64_m = (N_M + 63) / 64;
    int nb64_j = (N_J + 63) / 64;
    int nbE3   = (ETOT + 255) / 256;

    k_vdst<<<1, 64, 0, stream>>>(gat_w_dst, gat_att_d, v_dst);
    k_muon_prep<<<nb64_m, 256, 0, stream>>>(x_muons, gat_w_src, gat_att_s, v_dst, hs, as_, ad_);
    k_gcn_xw<<<nb64_j, 256, 0, stream>>>(x_jets, gcn_w, xw);

    k_hist<<<nbE3, 256, 0, stream>>>(ei_mm, ei_mj, ei_jj, cnt);
    k_scan1<<<NB_SCAN, 256, 0, stream>>>(cnt, offs, bsum);
    k_scan2<<<1, 512, 0, stream>>>(bsum);
    k_scan3<<<NB_SCAN, 256, 0, stream>>>(offs, bsum);
    k_fill<<<nbE3, 256, 0, stream>>>(ei_mm, ei_mj, ei_jj, offs, cursor, perm);
    k_dis<<<(N_J + 255)/256, 256, 0, stream>>>(offs, dis);

    k_muon_gat_out<<<N_M/4, 256, 0, stream>>>(offs, perm, as_, ad_, hs,
                                              gat_bias, lin_w, lin_b, out);
    k_jet_out<<<(N_J + 7)/8, 512, 0, stream>>>(x_jets, x_muons, xw, dis, offs, perm,
                                               sage_w_l, sage_w_r, sage_bias, gcn_bias,
                                               lin_w, lin_b, out);
}

// Round 4
// 509.568 us; speedup vs baseline: 36.1800x; 1.7823x over previous
//
#include <hip/hip_runtime.h>
#include <math.h>

#define N_M 100000
#define N_J 100000
#define NE  1600000
#define NTOT (3*N_M)          // 300000 buckets (mm | mj | jj)
#define ETOT (3*NE)           // 4800000 edges
#define NB_SCAN 293           // ceil(300000/1024)  (fallback path)
#define DD  64
#define HH  64

// 2-level CSR build: 586 coarse bins x 512 buckets/bin
#define NBIN 586
#define BIN_SHIFT 9           // 512 buckets per bin
#define G1 640                // blocks for bin passes
#define EPB ((ETOT + G1 - 1) / G1)   // 7500 edges per block

__device__ __forceinline__ float lrelu(float a){ return a > 0.f ? a : 0.2f*a; }
__device__ __forceinline__ float wmax(float v){
    #pragma unroll
    for (int o = 32; o; o >>= 1) v = fmaxf(v, __shfl_xor(v, o));
    return v;
}
__device__ __forceinline__ float wsum(float v){
    #pragma unroll
    for (int o = 32; o; o >>= 1) v += __shfl_xor(v, o);
    return v;
}
__device__ __forceinline__ float sigm(float x){ return 1.f/(1.f + expf(-x)); }

// ---------------- dense prep ----------------

__global__ void k_vdst(const float* __restrict__ w_dst, const float* __restrict__ att_dst,
                       float* __restrict__ v_dst){
    int d = threadIdx.x;
    float s = 0.f;
    for (int h = 0; h < HH; ++h) s += w_dst[d*HH + h] * att_dst[h];
    v_dst[d] = s;
}

__global__ __launch_bounds__(256) void k_muon_prep(
    const float* __restrict__ x, const float* __restrict__ w_src,
    const float* __restrict__ att_src, const float* __restrict__ v_dst,
    float* __restrict__ hs, float* __restrict__ as_, float* __restrict__ ad_)
{
    __shared__ float lw[DD*HH];
    __shared__ float latt[HH];
    __shared__ float lvd[DD];
    int tid = threadIdx.x;
    for (int i = tid; i < DD*HH; i += 256) lw[i] = w_src[i];
    if (tid < HH) latt[tid] = att_src[tid];
    if (tid < DD) lvd[tid] = v_dst[tid];
    __syncthreads();
    int row = blockIdx.x*64 + (tid >> 2);
    int q = tid & 3;
    if (row >= N_M) return;
    const float4* x4 = (const float4*)(x + (size_t)row*DD);
    float acc[16];
    #pragma unroll
    for (int f = 0; f < 16; ++f) acc[f] = 0.f;
    float adp = 0.f;
    for (int kk = 0; kk < 16; ++kk){
        float4 xv = x4[kk];
        adp += xv.x*lvd[4*kk] + xv.y*lvd[4*kk+1] + xv.z*lvd[4*kk+2] + xv.w*lvd[4*kk+3];
        float xs[4] = {xv.x, xv.y, xv.z, xv.w};
        #pragma unroll
        for (int j = 0; j < 4; ++j){
            const float* wp = lw + (4*kk + j)*HH + (q << 4);
            float xk = xs[j];
            #pragma unroll
            for (int f = 0; f < 16; ++f) acc[f] = fmaf(xk, wp[f], acc[f]);
        }
    }
    float asp = 0.f;
    #pragma unroll
    for (int f = 0; f < 16; ++f) asp += acc[f] * latt[(q<<4) + f];
    asp += __shfl_xor(asp, 1);
    asp += __shfl_xor(asp, 2);
    float* hp = hs + (size_t)row*HH + (q << 4);
    #pragma unroll
    for (int j = 0; j < 4; ++j)
        ((float4*)hp)[j] = make_float4(acc[4*j], acc[4*j+1], acc[4*j+2], acc[4*j+3]);
    if (q == 0){ as_[row] = asp; ad_[row] = adp; }
}

__global__ __launch_bounds__(256) void k_gcn_xw(
    const float* __restrict__ x, const float* __restrict__ w, float* __restrict__ xw)
{
    __shared__ float lw[DD*HH];
    int tid = threadIdx.x;
    for (int i = tid; i < DD*HH; i += 256) lw[i] = w[i];
    __syncthreads();
    int row = blockIdx.x*64 + (tid >> 2);
    int q = tid & 3;
    if (row >= N_J) return;
    const float4* x4 = (const float4*)(x + (size_t)row*DD);
    float acc[16];
    #pragma unroll
    for (int f = 0; f < 16; ++f) acc[f] = 0.f;
    for (int kk = 0; kk < 16; ++kk){
        float4 xv = x4[kk];
        float xs[4] = {xv.x, xv.y, xv.z, xv.w};
        #pragma unroll
        for (int j = 0; j < 4; ++j){
            const float* wp = lw + (4*kk + j)*HH + (q << 4);
            float xk = xs[j];
            #pragma unroll
            for (int f = 0; f < 16; ++f) acc[f] = fmaf(xk, wp[f], acc[f]);
        }
    }
    float* hp = xw + (size_t)row*HH + (q << 4);
    #pragma unroll
    for (int j = 0; j < 4; ++j)
        ((float4*)hp)[j] = make_float4(acc[4*j], acc[4*j+1], acc[4*j+2], acc[4*j+3]);
}

// ---------------- NEW: 2-level CSR build ----------------

__device__ __forceinline__ void edge_rd(int t, const int* ei_mm, const int* ei_mj,
                                        const int* ei_jj, const int** ei, int* r, int* e){
    if (t < NE){ *r = 0; *e = t; *ei = ei_mm; }
    else if (t < 2*NE){ *r = 1; *e = t - NE; *ei = ei_mj; }
    else { *r = 2; *e = t - 2*NE; *ei = ei_jj; }
}

// coarse bin histogram
__global__ __launch_bounds__(256) void k_bin0(
    const int* __restrict__ ei_mm, const int* __restrict__ ei_mj,
    const int* __restrict__ ei_jj, int* __restrict__ g_bincnt)
{
    __shared__ int bh[NBIN];
    int tid = threadIdx.x;
    for (int i = tid; i < NBIN; i += 256) bh[i] = 0;
    __syncthreads();
    int t0 = blockIdx.x * EPB;
    int t1 = min(t0 + EPB, ETOT);
    for (int t = t0 + tid; t < t1; t += 256){
        const int* ei; int r, e;
        edge_rd(t, ei_mm, ei_mj, ei_jj, &ei, &r, &e);
        int bucket = r*N_M + ei[NE + e];
        atomicAdd(&bh[bucket >> BIN_SHIFT], 1);
    }
    __syncthreads();
    for (int i = tid; i < NBIN; i += 256)
        if (bh[i]) atomicAdd(&g_bincnt[i], bh[i]);
}

// exclusive scan over NBIN (single wave), init cursors, set offs[NTOT]
__global__ void k_binscan(const int* __restrict__ g_bincnt, int* __restrict__ g_binoff,
                          int* __restrict__ g_bincur, int* __restrict__ offs)
{
    int l = threadIdx.x;            // 0..63
    int base = l * 10;              // 64*10 = 640 >= NBIN
    int v[10]; int s = 0;
    #pragma unroll
    for (int k = 0; k < 10; ++k){
        int idx = base + k;
        v[k] = (idx < NBIN) ? g_bincnt[idx] : 0;
        s += v[k];
    }
    int inc = s;
    #pragma unroll
    for (int o = 1; o < 64; o <<= 1){
        int u = __shfl_up(inc, o);
        if (l >= o) inc += u;
    }
    int ex = inc - s;
    #pragma unroll
    for (int k = 0; k < 10; ++k){
        int idx = base + k;
        if (idx < NBIN){ g_binoff[idx] = ex; g_bincur[idx] = ex; ex += v[k]; }
    }
    if (l == 63) g_binoff[NBIN] = ex;   // == ETOT
    if (l == 0)  offs[NTOT] = ETOT;
}

// scatter edges into bin-grouped order, packed (local_bucket<<17)|src
__global__ __launch_bounds__(256) void k_bin1(
    const int* __restrict__ ei_mm, const int* __restrict__ ei_mj,
    const int* __restrict__ ei_jj, int* __restrict__ g_bincur,
    unsigned* __restrict__ binned)
{
    __shared__ int bh[NBIN];
    __shared__ int cb[NBIN];
    int tid = threadIdx.x;
    for (int i = tid; i < NBIN; i += 256) bh[i] = 0;
    __syncthreads();
    int t0 = blockIdx.x * EPB;
    int t1 = min(t0 + EPB, ETOT);
    for (int t = t0 + tid; t < t1; t += 256){
        const int* ei; int r, e;
        edge_rd(t, ei_mm, ei_mj, ei_jj, &ei, &r, &e);
        int bucket = r*N_M + ei[NE + e];
        atomicAdd(&bh[bucket >> BIN_SHIFT], 1);
    }
    __syncthreads();
    for (int i = tid; i < NBIN; i += 256){
        int c = bh[i];
        cb[i] = c ? atomicAdd(&g_bincur[i], c) : 0;
        bh[i] = 0;                  // reuse as local cursor
    }
    __syncthreads();
    for (int t = t0 + tid; t < t1; t += 256){
        const int* ei; int r, e;
        edge_rd(t, ei_mm, ei_mj, ei_jj, &ei, &r, &e);
        int s = ei[e];
        int bucket = r*N_M + ei[NE + e];
        int bin = bucket >> BIN_SHIFT;
        int lb  = bucket & 511;
        int pos = cb[bin] + atomicAdd(&bh[bin], 1);
        binned[pos] = ((unsigned)lb << 17) | (unsigned)s;
    }
}

// per-bin: fine histogram + scan -> offs, then place srcs into perm
__global__ __launch_bounds__(256) void k_build(
    const unsigned* __restrict__ binned, const int* __restrict__ g_binoff,
    int* __restrict__ offs, int* __restrict__ perm)
{
    __shared__ int lh[512];
    __shared__ int lcur[512];
    __shared__ int ls[256];
    int b = blockIdx.x, tid = threadIdx.x;
    int e0 = g_binoff[b], e1 = g_binoff[b+1];
    lh[tid] = 0; lh[tid + 256] = 0;
    __syncthreads();
    for (int e = e0 + tid; e < e1; e += 256)
        atomicAdd(&lh[binned[e] >> 17], 1);
    __syncthreads();
    int a0 = lh[2*tid], a1 = lh[2*tid + 1];
    int s = a0 + a1;
    ls[tid] = s; __syncthreads();
    for (int o = 1; o < 256; o <<= 1){
        int u = (tid >= o) ? ls[tid - o] : 0;
        __syncthreads();
        ls[tid] += u;
        __syncthreads();
    }
    int ex = ls[tid] - s;
    lcur[2*tid]     = ex;
    lcur[2*tid + 1] = ex + a0;
    int gb = b*512 + 2*tid;
    if (gb     < NTOT) offs[gb]     = e0 + ex;
    if (gb + 1 < NTOT) offs[gb + 1] = e0 + ex + a0;
    __syncthreads();
    for (int e = e0 + tid; e < e1; e += 256){
        unsigned p = binned[e];
        int pos = atomicAdd(&lcur[p >> 17], 1);
        perm[e0 + pos] = (int)(p & 0x1FFFFu);
    }
}

// ---------------- fallback CSR build (R3 path, used if ws too small) ----------------

__global__ void k_hist(const int* __restrict__ ei_mm, const int* __restrict__ ei_mj,
                       const int* __restrict__ ei_jj, int* __restrict__ cnt){
    int t = blockIdx.x*256 + threadIdx.x;
    if (t >= ETOT) return;
    const int* ei; int r, e;
    edge_rd(t, ei_mm, ei_mj, ei_jj, &ei, &r, &e);
    atomicAdd(&cnt[r*N_M + ei[NE + e]], 1);
}

__global__ __launch_bounds__(256) void k_scan1(const int* __restrict__ cnt,
                                               int* __restrict__ offs, int* __restrict__ bsum){
    __shared__ int ls[256];
    int b = blockIdx.x, t = threadIdx.x;
    int base = b*1024 + t*4;
    int4 c = make_int4(0,0,0,0);
    if (base < NTOT) c = *(const int4*)(cnt + base);
    int s = c.x + c.y + c.z + c.w;
    ls[t] = s; __syncthreads();
    for (int o = 1; o < 256; o <<= 1){
        int a = (t >= o) ? ls[t - o] : 0;
        __syncthreads();
        ls[t] += a;
        __syncthreads();
    }
    int excl = ls[t] - s;
    if (t == 255) bsum[b] = ls[255];
    if (base < NTOT){
        offs[base]   = excl;
        offs[base+1] = excl + c.x;
        offs[base+2] = excl + c.x + c.y;
        offs[base+3] = excl + c.x + c.y + c.z;
    }
}

__global__ __launch_bounds__(512) void k_scan2(int* __restrict__ bsum){
    __shared__ int ls[512];
    int t = threadIdx.x;
    int v = (t < NB_SCAN) ? bsum[t] : 0;
    ls[t] = v; __syncthreads();
    for (int o = 1; o < 512; o <<= 1){
        int a = (t >= o) ? ls[t - o] : 0;
        __syncthreads();
        ls[t] += a;
        __syncthreads();
    }
    if (t < NB_SCAN) bsum[t] = ls[t] - v;
}

__global__ void k_scan3(int* __restrict__ offs, const int* __restrict__ bsum){
    int b = blockIdx.x, t = threadIdx.x;
    int base = b*1024 + t*4;
    if (base >= NTOT) return;
    int add = bsum[b];
    int4* p = (int4*)(offs + base);
    int4 v = *p;
    v.x += add; v.y += add; v.z += add; v.w += add;
    *p = v;
}

__global__ void k_fill(const int* __restrict__ ei_mm, const int* __restrict__ ei_mj,
                       const int* __restrict__ ei_jj, const int* __restrict__ offs,
                       int* __restrict__ cursor, int* __restrict__ perm){
    int t = blockIdx.x*256 + threadIdx.x;
    if (t >= ETOT) return;
    const int* ei; int r, e;
    edge_rd(t, ei_mm, ei_mj, ei_jj, &ei, &r, &e);
    int s = ei[e];
    int bkt = r*N_M + ei[NE + e];
    int pos = atomicAdd(&cursor[bkt], 1);
    perm[offs[bkt] + pos] = s;
}

__global__ void k_set_offs_top(int* __restrict__ offs){ offs[NTOT] = ETOT; }

// dis[j] = rsqrt(in-degree(jj) + 1)
__global__ void k_dis(const int* __restrict__ offs, float* __restrict__ dis){
    int j = blockIdx.x*256 + threadIdx.x;
    if (j >= N_J) return;
    int beg = offs[2*N_M + j];
    int end = (j == N_J-1) ? ETOT : offs[2*N_M + j + 1];
    dis[j] = rsqrtf((float)(end - beg + 1));
}

// ---------------- fused gather + epilogue ----------------

__global__ __launch_bounds__(256) void k_muon_gat_out(
    const int* __restrict__ offs, const int* __restrict__ perm,
    const float* __restrict__ as_, const float* __restrict__ ad_,
    const float* __restrict__ hs, const float* __restrict__ gat_bias,
    const float* __restrict__ lin_w, const float* __restrict__ lin_b,
    float* __restrict__ out)
{
    int wid = threadIdx.x >> 6;
    int l = threadIdx.x & 63;
    int d = blockIdx.x*4 + wid;
    if (d >= N_M) return;
    int beg = offs[d], end = offs[d+1];
    float ad_d = ad_[d];
    float a_self = lrelu(as_[d] + ad_d);
    float am = a_self;
    for (int base = beg; base < end; base += 64){
        int e = base + l;
        if (e < end) am = fmaxf(am, lrelu(as_[perm[e]] + ad_d));
    }
    float m = wmax(am);
    float eself = expf(a_self - m);
    float z = eself;
    float acc0 = eself * hs[(size_t)d*HH + l], acc1 = 0.f;
    for (int base = beg; base < end; base += 64){
        int e = base + l;
        int sB = 0; float eaB = 0.f;
        if (e < end){
            sB = perm[e];
            eaB = expf(lrelu(as_[sB] + ad_d) - m);
        }
        z += wsum(eaB);
        int cc = min(64, end - base);
        int k = 0;
        for (; k + 8 <= cc; k += 8){
            int s0=__shfl(sB,k+0), s1=__shfl(sB,k+1), s2=__shfl(sB,k+2), s3=__shfl(sB,k+3);
            int s4=__shfl(sB,k+4), s5=__shfl(sB,k+5), s6=__shfl(sB,k+6), s7=__shfl(sB,k+7);
            float e0=__shfl(eaB,k+0), e1=__shfl(eaB,k+1), e2=__shfl(eaB,k+2), e3=__shfl(eaB,k+3);
            float e4=__shfl(eaB,k+4), e5=__shfl(eaB,k+5), e6=__shfl(eaB,k+6), e7=__shfl(eaB,k+7);
            float v0=hs[(size_t)s0*HH+l], v1=hs[(size_t)s1*HH+l];
            float v2=hs[(size_t)s2*HH+l], v3=hs[(size_t)s3*HH+l];
            float v4=hs[(size_t)s4*HH+l], v5=hs[(size_t)s5*HH+l];
            float v6=hs[(size_t)s6*HH+l], v7=hs[(size_t)s7*HH+l];
            acc0 = fmaf(e0,v0,acc0); acc1 = fmaf(e1,v1,acc1);
            acc0 = fmaf(e2,v2,acc0); acc1 = fmaf(e3,v3,acc1);
            acc0 = fmaf(e4,v4,acc0); acc1 = fmaf(e5,v5,acc1);
            acc0 = fmaf(e6,v6,acc0); acc1 = fmaf(e7,v7,acc1);
        }
        for (; k < cc; ++k){
            int sk = __shfl(sB, k);
            float eak = __shfl(eaB, k);
            acc0 = fmaf(eak, hs[(size_t)sk*HH + l], acc0);
        }
    }
    float val = fmaxf((acc0 + acc1) / z + gat_bias[l], 0.f);
    float p0 = wsum(val * lin_w[l*2 + 0]);
    float p1 = wsum(val * lin_w[l*2 + 1]);
    if (l == 0){
        size_t o = (size_t)d*2;
        out[o]   = sigm(p0 + lin_b[0]);
        out[o+1] = sigm(p1 + lin_b[1]);
    }
}

__global__ __launch_bounds__(512) void k_jet_out(
    const float* __restrict__ x_jets, const float* __restrict__ x_muons,
    const float* __restrict__ xw, const float* __restrict__ dis,
    const int* __restrict__ offs, const int* __restrict__ perm,
    const float* __restrict__ w_l, const float* __restrict__ w_r,
    const float* __restrict__ sage_bias, const float* __restrict__ gcn_bias,
    const float* __restrict__ lin_w, const float* __restrict__ lin_b,
    float* __restrict__ out)
{
    __shared__ float lwl[DD*HH];
    __shared__ float lwr[DD*HH];
    int tid = threadIdx.x;
    for (int i = tid; i < DD*HH; i += 512){ lwl[i] = w_l[i]; lwr[i] = w_r[i]; }
    __syncthreads();
    int wid = tid >> 6;
    int l = tid & 63;
    int j = blockIdx.x*8 + wid;
    if (j >= N_J) return;
    int beg = offs[N_M + j], end = offs[N_M + j + 1];
    float sa0 = 0.f, sa1 = 0.f;
    for (int base = beg; base < end; base += 64){
        int e = base + l;
        int sB = (e < end) ? perm[e] : 0;
        int cc = min(64, end - base);
        int k = 0;
        for (; k + 8 <= cc; k += 8){
            int s0=__shfl(sB,k+0), s1=__shfl(sB,k+1), s2=__shfl(sB,k+2), s3=__shfl(sB,k+3);
            int s4=__shfl(sB,k+4), s5=__shfl(sB,k+5), s6=__shfl(sB,k+6), s7=__shfl(sB,k+7);
            float v0=x_muons[(size_t)s0*DD+l], v1=x_muons[(size_t)s1*DD+l];
            float v2=x_muons[(size_t)s2*DD+l], v3=x_muons[(size_t)s3*DD+l];
            float v4=x_muons[(size_t)s4*DD+l], v5=x_muons[(size_t)s5*DD+l];
            float v6=x_muons[(size_t)s6*DD+l], v7=x_muons[(size_t)s7*DD+l];
            sa0 += v0 + v2; sa1 += v1 + v3;
            sa0 += v4 + v6; sa1 += v5 + v7;
        }
        for (; k < cc; ++k){
            int sk = __shfl(sB, k);
            sa0 += x_muons[(size_t)sk*DD + l];
        }
    }
    float inv = (end > beg) ? 1.f/(float)(end - beg) : 1.f;
    float mean = (sa0 + sa1) * inv;
    int beg2 = offs[2*N_M + j];
    int end2 = (j == N_J-1) ? ETOT : offs[2*N_M + j + 1];
    float dj = dis[j];
    float g0 = dj*dj*xw[(size_t)j*HH + l], g1 = 0.f;
    for (int base = beg2; base < end2; base += 64){
        int e = base + l;
        int sB = 0; float nB = 0.f;
        if (e < end2){ sB = perm[e]; nB = dis[sB]*dj; }
        int cc = min(64, end2 - base);
        int k = 0;
        for (; k + 8 <= cc; k += 8){
            int s0=__shfl(sB,k+0), s1=__shfl(sB,k+1), s2=__shfl(sB,k+2), s3=__shfl(sB,k+3);
            int s4=__shfl(sB,k+4), s5=__shfl(sB,k+5), s6=__shfl(sB,k+6), s7=__shfl(sB,k+7);
            float n0=__shfl(nB,k+0), n1=__shfl(nB,k+1), n2=__shfl(nB,k+2), n3=__shfl(nB,k+3);
            float n4=__shfl(nB,k+4), n5=__shfl(nB,k+5), n6=__shfl(nB,k+6), n7=__shfl(nB,k+7);
            float v0=xw[(size_t)s0*HH+l], v1=xw[(size_t)s1*HH+l];
            float v2=xw[(size_t)s2*HH+l], v3=xw[(size_t)s3*HH+l];
            float v4=xw[(size_t)s4*HH+l], v5=xw[(size_t)s5*HH+l];
            float v6=xw[(size_t)s6*HH+l], v7=xw[(size_t)s7*HH+l];
            g0 = fmaf(n0,v0,g0); g1 = fmaf(n1,v1,g1);
            g0 = fmaf(n2,v2,g0); g1 = fmaf(n3,v3,g1);
            g0 = fmaf(n4,v4,g0); g1 = fmaf(n5,v5,g1);
            g0 = fmaf(n6,v6,g0); g1 = fmaf(n7,v7,g1);
        }
        for (; k < cc; ++k){
            int sk = __shfl(sB, k);
            float nk = __shfl(nB, k);
            g0 = fmaf(nk, xw[(size_t)sk*HH + l], g0);
        }
    }
    float xv = x_jets[(size_t)j*DD + l];
    float accf = g0 + g1 + gcn_bias[l] + sage_bias[l];
    for (int k = 0; k < 64; ++k){
        float mk = __shfl(mean, k);
        float xk = __shfl(xv, k);
        accf = fmaf(mk, lwl[k*64 + l], fmaf(xk, lwr[k*64 + l], accf));
    }
    float val = fmaxf(accf, 0.f);
    float p0 = wsum(val * lin_w[l*2 + 0]);
    float p1 = wsum(val * lin_w[l*2 + 1]);
    if (l == 0){
        size_t o = (size_t)(N_M + j)*2;
        out[o]   = sigm(p0 + lin_b[0]);
        out[o+1] = sigm(p1 + lin_b[1]);
    }
}

extern "C" void kernel_launch(void* const* d_in, const int* in_sizes, int n_in,
                              void* d_out, int out_size, void* d_ws, size_t ws_size,
                              hipStream_t stream) {
    const float* x_muons   = (const float*)d_in[0];
    const float* x_jets    = (const float*)d_in[1];
    const int*   ei_mm     = (const int*)d_in[2];
    const int*   ei_mj     = (const int*)d_in[3];
    const int*   ei_jj     = (const int*)d_in[4];
    const float* gat_w_src = (const float*)d_in[5];
    const float* gat_w_dst = (const float*)d_in[6];
    const float* gat_att_s = (const float*)d_in[7];
    const float* gat_att_d = (const float*)d_in[8];
    const float* gat_bias  = (const float*)d_in[9];
    const float* sage_w_l  = (const float*)d_in[10];
    const float* sage_w_r  = (const float*)d_in[11];
    const float* sage_bias = (const float*)d_in[12];
    const float* gcn_w     = (const float*)d_in[13];
    const float* gcn_bias  = (const float*)d_in[14];
    const float* lin_w     = (const float*)d_in[15];
    const float* lin_b     = (const float*)d_in[16];
    float* out = (float*)d_out;

    float* ws = (float*)d_ws;
    size_t o = 0;
    float* hs    = ws + o; o += (size_t)N_M*HH;
    float* as_   = ws + o; o += N_M;
    float* ad_   = ws + o; o += N_M;
    float* xw    = ws + o; o += (size_t)N_J*HH;
    float* dis   = ws + o; o += N_J;
    float* v_dst = ws + o; o += 64;
    int* offs   = (int*)(ws + o); o += NTOT + 4;
    int* perm   = (int*)(ws + o); o += ETOT;
    size_t o_common = o;

    int nb64_m = (N_M + 63) / 64;
    int nb64_j = (N_J + 63) / 64;

    k_vdst<<<1, 64, 0, stream>>>(gat_w_dst, gat_att_d, v_dst);
    k_muon_prep<<<nb64_m, 256, 0, stream>>>(x_muons, gat_w_src, gat_att_s, v_dst, hs, as_, ad_);
    k_gcn_xw<<<nb64_j, 256, 0, stream>>>(x_jets, gcn_w, xw);

    // fast 2-level build needs binned[ETOT] + bin arrays; check scratch budget
    size_t need_fast = (o_common + ETOT + 3*NBIN + 16) * sizeof(float);
    if (ws_size >= need_fast){
        unsigned* binned = (unsigned*)(ws + o); o += ETOT;
        int* g_bincnt    = (int*)(ws + o); o += NBIN;
        int* g_binoff    = (int*)(ws + o); o += NBIN + 4;
        int* g_bincur    = (int*)(ws + o); o += NBIN;
        hipMemsetAsync(g_bincnt, 0, NBIN*sizeof(int), stream);
        k_bin0<<<G1, 256, 0, stream>>>(ei_mm, ei_mj, ei_jj, g_bincnt);
        k_binscan<<<1, 64, 0, stream>>>(g_bincnt, g_binoff, g_bincur, offs);
        k_bin1<<<G1, 256, 0, stream>>>(ei_mm, ei_mj, ei_jj, g_bincur, binned);
        k_build<<<NBIN, 256, 0, stream>>>(binned, g_binoff, offs, perm);
    } else {
        // fallback: R3 path
        int* cnt    = (int*)(ws + o); o += NTOT;
        int* cursor = (int*)(ws + o); o += NTOT;
        int* bsum   = (int*)(ws + o); o += 512;
        hipMemsetAsync(cnt,    0, (size_t)NTOT*sizeof(int), stream);
        hipMemsetAsync(cursor, 0, (size_t)NTOT*sizeof(int), stream);
        int nbE3 = (ETOT + 255) / 256;
        k_hist<<<nbE3, 256, 0, stream>>>(ei_mm, ei_mj, ei_jj, cnt);
        k_scan1<<<NB_SCAN, 256, 0, stream>>>(cnt, offs, bsum);
        k_scan2<<<1, 512, 0, stream>>>(bsum);
        k_scan3<<<NB_SCAN, 256, 0, stream>>>(offs, bsum);
        k_fill<<<nbE3, 256, 0, stream>>>(ei_mm, ei_mj, ei_jj, offs, cursor, perm);
        k_set_offs_top<<<1, 1, 0, stream>>>(offs);
    }

    k_dis<<<(N_J + 255)/256, 256, 0, stream>>>(offs, dis);

    k_muon_gat_out<<<N_M/4, 256, 0, stream>>>(offs, perm, as_, ad_, hs,
                                              gat_bias, lin_w, lin_b, out);
    k_jet_out<<<(N_J + 7)/8, 512, 0, stream>>>(x_jets, x_muons, xw, dis, offs, perm,
                                               sage_w_l, sage_w_r, sage_bias, gcn_bias,
                                               lin_w, lin_b, out);
}